// Round 5
// baseline (8166.442 us; speedup 1.0000x reference)
//
#include <hip/hip_runtime.h>
#include <hip/hip_fp16.h>
#include <hip/hip_cooperative_groups.h>

namespace cg = cooperative_groups;

typedef _Float16 half8 __attribute__((ext_vector_type(8)));
typedef float floatx4 __attribute__((ext_vector_type(4)));

#define NB 128
#define NT 256
#define NIN 128
#define NH 1024

// ws layout (bytes): h ping-pong buffers + fp16 x copy + barrier state
#define H0_OFF   0u          // 2 * 128*1024 half = 524288 B
#define H1_OFF   524288u     // 524288 B
#define X16_OFF  1048576u    // 128*256*128 half = 8388608 B
#define BAR_OFF  9437184u    // barrier region: 16 group lines @256B, root @4096, flag @4352

// LDS layout (bytes), carved from extern __shared__:
//  w0l: 16 cols x (1152+8) half = 37120
//  w1l: 16 cols x (2048+8) half = 65792   (base 37120)
//  gs0: 16 cols x 132 float     =  8448   (base 102912) col-major gate tile
//  gs1: 16 cols x 132 float     =  8448   (base 111360)
//  bs0/bs1: 16+16 float         =   128   (base 119808) -> total 119936
#define W0STRIDE 1160
#define W1STRIDE 2056
#define GSTRIDE  132
#define LDS_BYTES 119936

__device__ __forceinline__ float sigm(float x) { return 1.0f / (1.0f + __expf(-x)); }
__device__ __forceinline__ float tanh_fast(float x) { return 1.0f - 2.0f / (__expf(2.0f * x) + 1.0f); }

// ---- LLC-coherent h exchange: agent-scope relaxed atomics bypass the
// ---- non-coherent per-XCD L2 (and L1), so NO cache fences are needed.
__device__ __forceinline__ half8 ld8_agent(const _Float16* p) {
    union { unsigned long long u[2]; half8 h; } r;
    r.u[0] = __hip_atomic_load((const unsigned long long*)p,
                               __ATOMIC_RELAXED, __HIP_MEMORY_SCOPE_AGENT);
    r.u[1] = __hip_atomic_load(((const unsigned long long*)p) + 1,
                               __ATOMIC_RELAXED, __HIP_MEMORY_SCOPE_AGENT);
    return r.h;
}
__device__ __forceinline__ void st2_agent(_Float16* p, float v) {
    _Float16 hv = (_Float16)v;
    unsigned short u;
    __builtin_memcpy(&u, &hv, 2);
    __hip_atomic_store((unsigned short*)p, u, __ATOMIC_RELAXED, __HIP_MEMORY_SCOPE_AGENT);
}

// Two-level grid barrier: 16 groups x 16 WGs, separate LLC lines. NO cache
// fences: all cross-WG data moves via agent-scope atomics (write-through /
// bypass), and __syncthreads before arrive drains vmcnt (stores at LLC).
__device__ __forceinline__ void gbar_arrive(char* bar, unsigned epoch, int wg) {
    unsigned* gcnt = (unsigned*)(bar + (wg & 15) * 256);
    unsigned old = __hip_atomic_fetch_add(gcnt, 1u, __ATOMIC_RELAXED, __HIP_MEMORY_SCOPE_AGENT);
    if (old == epoch * 16u - 1u) {        // last of my group
        unsigned* rcnt = (unsigned*)(bar + 4096);
        unsigned rold = __hip_atomic_fetch_add(rcnt, 1u, __ATOMIC_RELAXED, __HIP_MEMORY_SCOPE_AGENT);
        if (rold == epoch * 16u - 1u) {   // last group overall
            unsigned* flag = (unsigned*)(bar + 4352);
            __hip_atomic_store(flag, epoch, __ATOMIC_RELAXED, __HIP_MEMORY_SCOPE_AGENT);
        }
    }
}
__device__ __forceinline__ void gbar_wait(char* bar, unsigned epoch) {
    unsigned* flag = (unsigned*)(bar + 4352);
    while (__hip_atomic_load(flag, __ATOMIC_RELAXED, __HIP_MEMORY_SCOPE_AGENT) < epoch)
        __builtin_amdgcn_s_sleep(1);
}

__global__ void __launch_bounds__(512)
lstm_persist(const float* __restrict__ x,
             const float* __restrict__ Wih0, const float* __restrict__ Whh0,
             const float* __restrict__ bih0, const float* __restrict__ bhh0,
             const float* __restrict__ Wih1, const float* __restrict__ Whh1,
             const float* __restrict__ bih1, const float* __restrict__ bhh1,
             const float* __restrict__ Wd, const float* __restrict__ bd,
             float* __restrict__ out, char* __restrict__ wsc)
{
    cg::grid_group grid = cg::this_grid();
    const int wg   = blockIdx.x;      // 0..255, owns h-cols [wg*4, wg*4+4)
    const int tid  = threadIdx.x;     // 0..511
    const int wave = tid >> 6;        // 0..7, owns batch rows [wave*16, wave*16+16)
    const int lane = tid & 63;
    const int l15  = lane & 15;
    const int quad = lane >> 4;

    _Float16* h0b = (_Float16*)(wsc + H0_OFF);   // [2][128][1024]
    _Float16* h1b = (_Float16*)(wsc + H1_OFF);   // [2][128][1024]
    _Float16* x16 = (_Float16*)(wsc + X16_OFF);  // [128][256][128]
    char* bar = wsc + BAR_OFF;

    extern __shared__ char smem[];
    _Float16* w0l = (_Float16*)(smem);            // [16][1160]
    _Float16* w1l = (_Float16*)(smem + 37120);    // [16][2056]
    float*    gs0 = (float*)(smem + 102912);      // [16][132] col-major
    float*    gs1 = (float*)(smem + 111360);      // [16][132]
    float*    bs0 = (float*)(smem + 119808);      // [16]
    float*    bs1 = (float*)(smem + 119808 + 64); // [16]

    // ---------- init: stage this WG's weight slice into LDS (fp16) ----------
    for (int i = tid; i < 16 * 1152; i += 512) {
        int c = i / 1152, k = i - c * 1152;
        int gcol = ((c >> 2) << 10) + (wg << 2) + (c & 3);
        float v = (k < NIN) ? Wih0[gcol * NIN + k] : Whh0[gcol * NH + (k - NIN)];
        w0l[c * W0STRIDE + k] = (_Float16)v;
    }
    for (int i = tid; i < 16 * 2048; i += 512) {
        int c = i >> 11, k = i & 2047;
        int gcol = ((c >> 2) << 10) + (wg << 2) + (c & 3);
        float v = (k < NH) ? Wih1[gcol * NH + k] : Whh1[gcol * NH + (k - NH)];
        w1l[c * W1STRIDE + k] = (_Float16)v;
    }
    if (tid < 16) {
        int c = tid;
        int gcol = ((c >> 2) << 10) + (wg << 2) + (c & 3);
        bs0[c] = bih0[gcol] + bhh0[gcol];
        bs1[c] = bih1[gcol] + bhh1[gcol];
    }

    // ---------- init: zero h bufs, convert x to fp16, reset barrier state ----------
    {
        const int gtid = wg * 512 + tid;
        const int gsz  = 256 * 512;  // 131072
        float* hz = (float*)wsc;     // both h bufs = 1 MiB = 262144 floats
        for (int i = gtid; i < 262144; i += gsz) hz[i] = 0.0f;
        for (int i = gtid; i < NB * NT * NIN; i += gsz) x16[i] = (_Float16)x[i];
        if (wg == 0 && tid < 18) {   // d_ws is poisoned 0xAA each run
            if (tid < 16)       *(unsigned*)(bar + tid * 256) = 0u;  // group counters
            else if (tid == 16) *(unsigned*)(bar + 4096) = 0u;       // root counter
            else                *(unsigned*)(bar + 4352) = 0u;       // flag
        }
    }
    // one slow cg sync with full fences: publishes zeros (into LLC) + barrier state
    __builtin_amdgcn_fence(__ATOMIC_RELEASE, "agent");
    grid.sync();
    __builtin_amdgcn_fence(__ATOMIC_ACQUIRE, "agent");

    float c0 = 0.0f, c1 = 0.0f;          // persistent cell state, 1 (b,hcol) pair/thread
    const int b_act = tid >> 2;          // batch row for activation stage
    const int jl    = tid & 3;           // local h-col
    const int hcol  = (wg << 2) + jl;

    // B-fragment row bases in LDS (n = l15), A k-offset quad*8 baked in
    const _Float16* w0row = w0l + l15 * W0STRIDE + quad * 8;
    const _Float16* w1row = w1l + l15 * W1STRIDE + quad * 8;

    // x-part of layer0 gates for step p (h-independent, cached normally): K = 0..127
    auto xpart = [&](int p) -> floatx4 {
        floatx4 acc = {0.f, 0.f, 0.f, 0.f};
        const _Float16* arow_x = x16 + (size_t)(wave * 16 + l15) * (NT * NIN) + p * NIN + quad * 8;
        #pragma unroll
        for (int kc = 0; kc < 4; ++kc) {
            half8 a = *(const half8*)(arow_x + kc * 32);
            half8 b = *(const half8*)(w0row + kc * 32);
            acc = __builtin_amdgcn_mfma_f32_16x16x32_f16(a, b, acc, 0, 0, 0);
        }
        return acc;
    };

    floatx4 accx = xpart(0);   // prologue for p=0

    // pipeline: phase p computes h0[p] (p<NT) and h1[p-1] (p>=1)
    for (int p = 0; p <= NT; ++p) {
        const _Float16* h0prev = h0b + ((p - 1) & 1) * (NB * NH);  // h0[p-1]
        const _Float16* h1pp   = h1b + (p & 1) * (NB * NH);        // h1[p-2]

        floatx4 acc0 = accx;   // x contribution precomputed during prior barrier window
        floatx4 acc1 = {0.f, 0.f, 0.f, 0.f};

        const _Float16* arow_h0 = h0prev + (size_t)(wave * 16 + l15) * NH + quad * 8;

        // h0[p-1] contribution: feeds BOTH layer0 (W_hh0) and layer1 (W_ih1) — share A loads
        if (p >= 1 && p < NT) {
            const _Float16* b0 = w0row + NIN;
            #pragma unroll 8
            for (int kc = 0; kc < 32; ++kc) {
                half8 a  = ld8_agent(arow_h0 + kc * 32);
                half8 v0 = *(const half8*)(b0 + kc * 32);
                half8 v1 = *(const half8*)(w1row + kc * 32);
                acc0 = __builtin_amdgcn_mfma_f32_16x16x32_f16(a, v0, acc0, 0, 0, 0);
                acc1 = __builtin_amdgcn_mfma_f32_16x16x32_f16(a, v1, acc1, 0, 0, 0);
            }
        } else if (p < NT) {  // p == 0
            const _Float16* b0 = w0row + NIN;
            #pragma unroll 8
            for (int kc = 0; kc < 32; ++kc) {
                half8 a  = ld8_agent(arow_h0 + kc * 32);
                half8 v0 = *(const half8*)(b0 + kc * 32);
                acc0 = __builtin_amdgcn_mfma_f32_16x16x32_f16(a, v0, acc0, 0, 0, 0);
            }
        } else {              // p == NT
            #pragma unroll 8
            for (int kc = 0; kc < 32; ++kc) {
                half8 a  = ld8_agent(arow_h0 + kc * 32);
                half8 v1 = *(const half8*)(w1row + kc * 32);
                acc1 = __builtin_amdgcn_mfma_f32_16x16x32_f16(a, v1, acc1, 0, 0, 0);
            }
        }

        if (p >= 1) {
            // h1[p-2] contribution to layer1 gates (K = 1024..2047)
            const _Float16* arow_h1 = h1pp + (size_t)(wave * 16 + l15) * NH + quad * 8;
            const _Float16* b1 = w1row + NH;
            #pragma unroll 8
            for (int kc = 0; kc < 32; ++kc) {
                half8 a = ld8_agent(arow_h1 + kc * 32);
                half8 v = *(const half8*)(b1 + kc * 32);
                acc1 = __builtin_amdgcn_mfma_f32_16x16x32_f16(a, v, acc1, 0, 0, 0);
            }
        }

        // stash gate tiles to LDS, col-major: rows quad*4+r contiguous -> one b128
        if (p < NT) *(floatx4*)&gs0[l15 * GSTRIDE + wave * 16 + quad * 4] = acc0;
        if (p >= 1) *(floatx4*)&gs1[l15 * GSTRIDE + wave * 16 + quad * 4] = acc1;
        __syncthreads();

        // activation: 1 (b, hcol) pair per thread; gate cols c = gate*4 + jl
        if (p < NT) {
            float gi = gs0[(jl)      * GSTRIDE + b_act] + bs0[jl];
            float gf = gs0[(4 + jl)  * GSTRIDE + b_act] + bs0[4 + jl];
            float gg = gs0[(8 + jl)  * GSTRIDE + b_act] + bs0[8 + jl];
            float go = gs0[(12 + jl) * GSTRIDE + b_act] + bs0[12 + jl];
            c0 = sigm(gf) * c0 + sigm(gi) * tanh_fast(gg);
            float h = sigm(go) * tanh_fast(c0);
            st2_agent(h0b + (p & 1) * (NB * NH) + b_act * NH + hcol, h);
        }
        if (p >= 1) {
            float gi = gs1[(jl)      * GSTRIDE + b_act] + bs1[jl];
            float gf = gs1[(4 + jl)  * GSTRIDE + b_act] + bs1[4 + jl];
            float gg = gs1[(8 + jl)  * GSTRIDE + b_act] + bs1[8 + jl];
            float go = gs1[(12 + jl) * GSTRIDE + b_act] + bs1[12 + jl];
            c1 = sigm(gf) * c1 + sigm(gi) * tanh_fast(gg);
            float h = sigm(go) * tanh_fast(c1);
            st2_agent(h1b + ((p - 1) & 1) * (NB * NH) + b_act * NH + hcol, h);
        }

        // ---- barrier with overlap: arrive, compute next x-part during spin window ----
        __syncthreads();                       // drains vmcnt: h-stores committed at LLC
        if (tid == 0) gbar_arrive(bar, (unsigned)(p + 1), wg);
        if (p + 1 < NT) accx = xpart(p + 1);   // h-independent work hides spin latency
        if (tid == 0) gbar_wait(bar, (unsigned)(p + 1));
        __syncthreads();
    }

    // dense head, parallel over batch: WG b computes out[b][0..1] from h1[255] (parity 1)
    if (wg < NB) {
        const _Float16* hrow = h1b + (NB * NH) + wg * NH;
        union { unsigned u; _Float16 h[2]; } cv;
        cv.u = __hip_atomic_load((const unsigned*)hrow + tid,
                                 __ATOMIC_RELAXED, __HIP_MEMORY_SCOPE_AGENT);
        float hk0 = (float)cv.h[0];
        float hk1 = (float)cv.h[1];
        float p0 = hk0 * Wd[tid * 2] + hk1 * Wd[tid * 2 + 1];
        float p1 = hk0 * Wd[NH + tid * 2] + hk1 * Wd[NH + tid * 2 + 1];
        #pragma unroll
        for (int off = 32; off; off >>= 1) {
            p0 += __shfl_down(p0, off);
            p1 += __shfl_down(p1, off);
        }
        float* red = gs0;  // reuse LDS (all threads past final __syncthreads)
        if (lane == 0) { red[wave * 2] = p0; red[wave * 2 + 1] = p1; }
        __syncthreads();
        if (tid < 2) {
            float s = bd[tid];
            #pragma unroll
            for (int w = 0; w < 8; ++w) s += red[w * 2 + tid];
            out[wg * 2 + tid] = tanhf(s);
        }
    }
}

extern "C" void kernel_launch(void* const* d_in, const int* in_sizes, int n_in,
                              void* d_out, int out_size, void* d_ws, size_t ws_size,
                              hipStream_t stream) {
    const float* x    = (const float*)d_in[0];
    const float* Wih0 = (const float*)d_in[1];
    const float* Whh0 = (const float*)d_in[2];
    const float* bih0 = (const float*)d_in[3];
    const float* bhh0 = (const float*)d_in[4];
    const float* Wih1 = (const float*)d_in[5];
    const float* Whh1 = (const float*)d_in[6];
    const float* bih1 = (const float*)d_in[7];
    const float* bhh1 = (const float*)d_in[8];
    const float* Wd   = (const float*)d_in[9];
    const float* bd   = (const float*)d_in[10];
    float* out = (float*)d_out;
    char* ws = (char*)d_ws;

    hipFuncSetAttribute((const void*)lstm_persist,
                        hipFuncAttributeMaxDynamicSharedMemorySize, LDS_BYTES);

    void* kargs[] = { &x, &Wih0, &Whh0, &bih0, &bhh0, &Wih1, &Whh1, &bih1, &bhh1,
                      &Wd, &bd, &out, &ws };
    hipLaunchCooperativeKernel((void*)lstm_persist, dim3(256), dim3(512),
                               kargs, LDS_BYTES, stream);
}

// Round 6
// 5096.649 us; speedup vs baseline: 1.6023x; 1.6023x over previous
//
#include <hip/hip_runtime.h>
#include <hip/hip_fp16.h>
#include <hip/hip_cooperative_groups.h>

namespace cg = cooperative_groups;

typedef _Float16 half8 __attribute__((ext_vector_type(8)));
typedef float floatx4 __attribute__((ext_vector_type(4)));

#define NB 128
#define NT 256
#define NIN 128
#define NH 1024

// ws layout (bytes): h ping-pong buffers + fp16 x copy + barrier state
#define H0_OFF   0u          // 2 * 128*1024 half = 524288 B
#define H1_OFF   524288u     // 524288 B
#define X16_OFF  1048576u    // 128*256*128 half = 8388608 B
#define BAR_OFF  9437184u    // barrier region: 16 group lines @256B, root @4096, flag @4352

// LDS layout (bytes), carved from extern __shared__:
//  w0l: 16 cols x (1152+8) half = 37120
//  w1l: 16 cols x (2048+8) half = 65792   (base 37120)
//  gs0: 16 cols x 132 float     =  8448   (base 102912) col-major gate tile
//  gs1: 16 cols x 132 float     =  8448   (base 111360)
//  bs0/bs1: 16+16 float         =   128   (base 119808) -> total 119936
#define W0STRIDE 1160
#define W1STRIDE 2056
#define GSTRIDE  132
#define LDS_BYTES 119936

__device__ __forceinline__ float sigm(float x) { return 1.0f / (1.0f + __expf(-x)); }
__device__ __forceinline__ float tanh_fast(float x) { return 1.0f - 2.0f / (__expf(2.0f * x) + 1.0f); }

// h STORES: agent-scope relaxed atomic 2B stores — write-through past the
// non-coherent XCD L2 straight to LLC. After __syncthreads' vmcnt(0) drain
// these are globally visible: NO release (wbl2) fence needed anywhere.
// (Empirically validated: R5 passed with no fences using these stores.)
__device__ __forceinline__ void st2_agent(_Float16* p, float v) {
    _Float16 hv = (_Float16)v;
    unsigned short u;
    __builtin_memcpy(&u, &hv, 2);
    __hip_atomic_store((unsigned short*)p, u, __ATOMIC_RELAXED, __HIP_MEMORY_SCOPE_AGENT);
}

// Two-level grid barrier: 16 groups x 16 WGs, separate LLC lines.
// Release side: NO cache fence (see st2_agent). Acquire side: one buffer_inv
// per CU (L1 + XCD-L2 invalidate) so subsequent CACHED loads refill from LLC.
__device__ __forceinline__ void gbar_arrive(char* bar, unsigned epoch, int wg) {
    unsigned* gcnt = (unsigned*)(bar + (wg & 15) * 256);
    unsigned old = __hip_atomic_fetch_add(gcnt, 1u, __ATOMIC_RELAXED, __HIP_MEMORY_SCOPE_AGENT);
    if (old == epoch * 16u - 1u) {        // last of my group
        unsigned* rcnt = (unsigned*)(bar + 4096);
        unsigned rold = __hip_atomic_fetch_add(rcnt, 1u, __ATOMIC_RELAXED, __HIP_MEMORY_SCOPE_AGENT);
        if (rold == epoch * 16u - 1u) {   // last group overall
            unsigned* flag = (unsigned*)(bar + 4352);
            __hip_atomic_store(flag, epoch, __ATOMIC_RELAXED, __HIP_MEMORY_SCOPE_AGENT);
        }
    }
}
__device__ __forceinline__ void gbar_wait(char* bar, unsigned epoch) {
    unsigned* flag = (unsigned*)(bar + 4352);
    while (__hip_atomic_load(flag, __ATOMIC_RELAXED, __HIP_MEMORY_SCOPE_AGENT) < epoch)
        __builtin_amdgcn_s_sleep(1);
    __builtin_amdgcn_fence(__ATOMIC_ACQUIRE, "agent");  // inv L1 + XCD L2
}

__global__ void __launch_bounds__(512)
lstm_persist(const float* __restrict__ x,
             const float* __restrict__ Wih0, const float* __restrict__ Whh0,
             const float* __restrict__ bih0, const float* __restrict__ bhh0,
             const float* __restrict__ Wih1, const float* __restrict__ Whh1,
             const float* __restrict__ bih1, const float* __restrict__ bhh1,
             const float* __restrict__ Wd, const float* __restrict__ bd,
             float* __restrict__ out, char* __restrict__ wsc)
{
    cg::grid_group grid = cg::this_grid();
    const int wg   = blockIdx.x;      // 0..255, owns h-cols [wg*4, wg*4+4)
    const int tid  = threadIdx.x;     // 0..511
    const int wave = tid >> 6;        // 0..7, owns batch rows [wave*16, wave*16+16)
    const int lane = tid & 63;
    const int l15  = lane & 15;
    const int quad = lane >> 4;

    _Float16* h0b = (_Float16*)(wsc + H0_OFF);   // [2][128][1024]
    _Float16* h1b = (_Float16*)(wsc + H1_OFF);   // [2][128][1024]
    _Float16* x16 = (_Float16*)(wsc + X16_OFF);  // [128][256][128]
    char* bar = wsc + BAR_OFF;

    extern __shared__ char smem[];
    _Float16* w0l = (_Float16*)(smem);            // [16][1160]
    _Float16* w1l = (_Float16*)(smem + 37120);    // [16][2056]
    float*    gs0 = (float*)(smem + 102912);      // [16][132] col-major
    float*    gs1 = (float*)(smem + 111360);      // [16][132]
    float*    bs0 = (float*)(smem + 119808);      // [16]
    float*    bs1 = (float*)(smem + 119808 + 64); // [16]

    // ---------- init: stage this WG's weight slice into LDS (fp16) ----------
    for (int i = tid; i < 16 * 1152; i += 512) {
        int c = i / 1152, k = i - c * 1152;
        int gcol = ((c >> 2) << 10) + (wg << 2) + (c & 3);
        float v = (k < NIN) ? Wih0[gcol * NIN + k] : Whh0[gcol * NH + (k - NIN)];
        w0l[c * W0STRIDE + k] = (_Float16)v;
    }
    for (int i = tid; i < 16 * 2048; i += 512) {
        int c = i >> 11, k = i & 2047;
        int gcol = ((c >> 2) << 10) + (wg << 2) + (c & 3);
        float v = (k < NH) ? Wih1[gcol * NH + k] : Whh1[gcol * NH + (k - NH)];
        w1l[c * W1STRIDE + k] = (_Float16)v;
    }
    if (tid < 16) {
        int c = tid;
        int gcol = ((c >> 2) << 10) + (wg << 2) + (c & 3);
        bs0[c] = bih0[gcol] + bhh0[gcol];
        bs1[c] = bih1[gcol] + bhh1[gcol];
    }

    // ---------- init: zero h bufs, convert x to fp16, reset barrier state ----------
    {
        const int gtid = wg * 512 + tid;
        const int gsz  = 256 * 512;  // 131072
        float* hz = (float*)wsc;     // both h bufs = 1 MiB = 262144 floats
        for (int i = gtid; i < 262144; i += gsz) hz[i] = 0.0f;
        for (int i = gtid; i < NB * NT * NIN; i += gsz) x16[i] = (_Float16)x[i];
        if (wg == 0 && tid < 18) {   // d_ws is poisoned 0xAA each run
            if (tid < 16)       *(unsigned*)(bar + tid * 256) = 0u;  // group counters
            else if (tid == 16) *(unsigned*)(bar + 4096) = 0u;       // root counter
            else                *(unsigned*)(bar + 4352) = 0u;       // flag
        }
    }
    // one slow cg sync with full fences: publishes zeros (into LLC) + barrier state
    __builtin_amdgcn_fence(__ATOMIC_RELEASE, "agent");
    grid.sync();
    __builtin_amdgcn_fence(__ATOMIC_ACQUIRE, "agent");

    float c0 = 0.0f, c1 = 0.0f;          // persistent cell state, 1 (b,hcol) pair/thread
    const int b_act = tid >> 2;          // batch row for activation stage
    const int jl    = tid & 3;           // local h-col
    const int hcol  = (wg << 2) + jl;

    // B-fragment row bases in LDS (n = l15), A k-offset quad*8 baked in
    const _Float16* w0row = w0l + l15 * W0STRIDE + quad * 8;
    const _Float16* w1row = w1l + l15 * W1STRIDE + quad * 8;

    // x-part of layer0 gates for step p (h-independent, cached normally): K = 0..127
    auto xpart = [&](int p) -> floatx4 {
        floatx4 acc = {0.f, 0.f, 0.f, 0.f};
        const _Float16* arow_x = x16 + (size_t)(wave * 16 + l15) * (NT * NIN) + p * NIN + quad * 8;
        #pragma unroll
        for (int kc = 0; kc < 4; ++kc) {
            half8 a = *(const half8*)(arow_x + kc * 32);
            half8 b = *(const half8*)(w0row + kc * 32);
            acc = __builtin_amdgcn_mfma_f32_16x16x32_f16(a, b, acc, 0, 0, 0);
        }
        return acc;
    };

    floatx4 accx = xpart(0);   // prologue for p=0

    // pipeline: phase p computes h0[p] (p<NT) and h1[p-1] (p>=1)
    for (int p = 0; p <= NT; ++p) {
        const _Float16* h0prev = h0b + ((p - 1) & 1) * (NB * NH);  // h0[p-1]
        const _Float16* h1pp   = h1b + (p & 1) * (NB * NH);        // h1[p-2]

        floatx4 acc0 = accx;   // x contribution precomputed during prior barrier window
        floatx4 acc1 = {0.f, 0.f, 0.f, 0.f};

        const _Float16* arow_h0 = h0prev + (size_t)(wave * 16 + l15) * NH + quad * 8;

        // h0[p-1] contribution: feeds BOTH layer0 (W_hh0) and layer1 (W_ih1) — share A loads
        if (p >= 1 && p < NT) {
            const _Float16* b0 = w0row + NIN;
            #pragma unroll 8
            for (int kc = 0; kc < 32; ++kc) {
                half8 a  = *(const half8*)(arow_h0 + kc * 32);
                half8 v0 = *(const half8*)(b0 + kc * 32);
                half8 v1 = *(const half8*)(w1row + kc * 32);
                acc0 = __builtin_amdgcn_mfma_f32_16x16x32_f16(a, v0, acc0, 0, 0, 0);
                acc1 = __builtin_amdgcn_mfma_f32_16x16x32_f16(a, v1, acc1, 0, 0, 0);
            }
        } else if (p < NT) {  // p == 0
            const _Float16* b0 = w0row + NIN;
            #pragma unroll 8
            for (int kc = 0; kc < 32; ++kc) {
                half8 a  = *(const half8*)(arow_h0 + kc * 32);
                half8 v0 = *(const half8*)(b0 + kc * 32);
                acc0 = __builtin_amdgcn_mfma_f32_16x16x32_f16(a, v0, acc0, 0, 0, 0);
            }
        } else {              // p == NT
            #pragma unroll 8
            for (int kc = 0; kc < 32; ++kc) {
                half8 a  = *(const half8*)(arow_h0 + kc * 32);
                half8 v1 = *(const half8*)(w1row + kc * 32);
                acc1 = __builtin_amdgcn_mfma_f32_16x16x32_f16(a, v1, acc1, 0, 0, 0);
            }
        }

        if (p >= 1) {
            // h1[p-2] contribution to layer1 gates (K = 1024..2047)
            const _Float16* arow_h1 = h1pp + (size_t)(wave * 16 + l15) * NH + quad * 8;
            const _Float16* b1 = w1row + NH;
            #pragma unroll 8
            for (int kc = 0; kc < 32; ++kc) {
                half8 a = *(const half8*)(arow_h1 + kc * 32);
                half8 v = *(const half8*)(b1 + kc * 32);
                acc1 = __builtin_amdgcn_mfma_f32_16x16x32_f16(a, v, acc1, 0, 0, 0);
            }
        }

        // stash gate tiles to LDS, col-major: rows quad*4+r contiguous -> one b128
        if (p < NT) *(floatx4*)&gs0[l15 * GSTRIDE + wave * 16 + quad * 4] = acc0;
        if (p >= 1) *(floatx4*)&gs1[l15 * GSTRIDE + wave * 16 + quad * 4] = acc1;
        __syncthreads();

        // activation: 1 (b, hcol) pair per thread; gate cols c = gate*4 + jl
        if (p < NT) {
            float gi = gs0[(jl)      * GSTRIDE + b_act] + bs0[jl];
            float gf = gs0[(4 + jl)  * GSTRIDE + b_act] + bs0[4 + jl];
            float gg = gs0[(8 + jl)  * GSTRIDE + b_act] + bs0[8 + jl];
            float go = gs0[(12 + jl) * GSTRIDE + b_act] + bs0[12 + jl];
            c0 = sigm(gf) * c0 + sigm(gi) * tanh_fast(gg);
            float h = sigm(go) * tanh_fast(c0);
            st2_agent(h0b + (p & 1) * (NB * NH) + b_act * NH + hcol, h);
        }
        if (p >= 1) {
            float gi = gs1[(jl)      * GSTRIDE + b_act] + bs1[jl];
            float gf = gs1[(4 + jl)  * GSTRIDE + b_act] + bs1[4 + jl];
            float gg = gs1[(8 + jl)  * GSTRIDE + b_act] + bs1[8 + jl];
            float go = gs1[(12 + jl) * GSTRIDE + b_act] + bs1[12 + jl];
            c1 = sigm(gf) * c1 + sigm(gi) * tanh_fast(gg);
            float h = sigm(go) * tanh_fast(c1);
            st2_agent(h1b + ((p - 1) & 1) * (NB * NH) + b_act * NH + hcol, h);
        }

        // ---- barrier with overlap: arrive (no release fence needed — h stores
        // ---- are LLC write-through and vmcnt-drained by __syncthreads),
        // ---- compute next x-part during spin window, then wait + acquire-inv.
        __syncthreads();                       // drains vmcnt: h-stores committed at LLC
        if (tid == 0) gbar_arrive(bar, (unsigned)(p + 1), wg);
        if (p + 1 < NT) accx = xpart(p + 1);   // h-independent work hides spin latency
        if (tid == 0) gbar_wait(bar, (unsigned)(p + 1));
        __syncthreads();
    }

    // dense head, parallel over batch: WG b computes out[b][0..1] from h1[255] (parity 1)
    // (final gbar_wait's acquire fence makes cached loads of h1 fresh)
    if (wg < NB) {
        const _Float16* hrow = h1b + (NB * NH) + wg * NH;
        float hk0 = (float)hrow[tid * 2];
        float hk1 = (float)hrow[tid * 2 + 1];
        float p0 = hk0 * Wd[tid * 2] + hk1 * Wd[tid * 2 + 1];
        float p1 = hk0 * Wd[NH + tid * 2] + hk1 * Wd[NH + tid * 2 + 1];
        #pragma unroll
        for (int off = 32; off; off >>= 1) {
            p0 += __shfl_down(p0, off);
            p1 += __shfl_down(p1, off);
        }
        float* red = gs0;  // reuse LDS (all threads past final __syncthreads)
        if (lane == 0) { red[wave * 2] = p0; red[wave * 2 + 1] = p1; }
        __syncthreads();
        if (tid < 2) {
            float s = bd[tid];
            #pragma unroll
            for (int w = 0; w < 8; ++w) s += red[w * 2 + tid];
            out[wg * 2 + tid] = tanhf(s);
        }
    }
}

extern "C" void kernel_launch(void* const* d_in, const int* in_sizes, int n_in,
                              void* d_out, int out_size, void* d_ws, size_t ws_size,
                              hipStream_t stream) {
    const float* x    = (const float*)d_in[0];
    const float* Wih0 = (const float*)d_in[1];
    const float* Whh0 = (const float*)d_in[2];
    const float* bih0 = (const float*)d_in[3];
    const float* bhh0 = (const float*)d_in[4];
    const float* Wih1 = (const float*)d_in[5];
    const float* Whh1 = (const float*)d_in[6];
    const float* bih1 = (const float*)d_in[7];
    const float* bhh1 = (const float*)d_in[8];
    const float* Wd   = (const float*)d_in[9];
    const float* bd   = (const float*)d_in[10];
    float* out = (float*)d_out;
    char* ws = (char*)d_ws;

    hipFuncSetAttribute((const void*)lstm_persist,
                        hipFuncAttributeMaxDynamicSharedMemorySize, LDS_BYTES);

    void* kargs[] = { &x, &Wih0, &Whh0, &bih0, &bhh0, &Wih1, &Whh1, &bih1, &bhh1,
                      &Wd, &bd, &out, &ws };
    hipLaunchCooperativeKernel((void*)lstm_persist, dim3(256), dim3(512),
                               kargs, LDS_BYTES, stream);
}

// Round 7
// 5074.880 us; speedup vs baseline: 1.6092x; 1.0043x over previous
//
#include <hip/hip_runtime.h>
#include <hip/hip_fp16.h>
#include <hip/hip_cooperative_groups.h>

namespace cg = cooperative_groups;

typedef _Float16 half8 __attribute__((ext_vector_type(8)));
typedef float floatx4 __attribute__((ext_vector_type(4)));

#define NB 128
#define NT 256
#define NIN 128
#define NH 1024

// ws layout (bytes): h ping-pong buffers + fp16 x copy + barrier state
#define H0_OFF   0u          // 2 * 128*1024 half = 524288 B
#define H1_OFF   524288u     // 524288 B
#define X16_OFF  1048576u    // 128*256*128 half = 8388608 B
#define BAR_OFF  9437184u    // barrier region: 16 group lines @256B, root @4096, flag @4352

// LDS layout (bytes), carved from extern __shared__:
//  w0l: 16 cols x (1152+8) half = 37120
//  w1l: 16 cols x (2048+8) half = 65792   (base 37120)
//  gs0: 16 cols x 132 float     =  8448   (base 102912) col-major gate tile
//  gs1: 16 cols x 132 float     =  8448   (base 111360)
//  bs0/bs1: 16+16 float         =   128   (base 119808) -> total 119936
#define W0STRIDE 1160
#define W1STRIDE 2056
#define GSTRIDE  132
#define LDS_BYTES 119936

__device__ __forceinline__ float sigm(float x) { return 1.0f / (1.0f + __expf(-x)); }
__device__ __forceinline__ float tanh_fast(float x) { return 1.0f - 2.0f / (__expf(2.0f * x) + 1.0f); }

// h STORES: agent-scope relaxed atomic 2B stores — write-through past the
// non-coherent XCD L2 straight to LLC. After __syncthreads' vmcnt(0) drain
// these are globally visible: NO release (wbl2) fence needed anywhere.
__device__ __forceinline__ void st2_agent(_Float16* p, float v) {
    _Float16 hv = (_Float16)v;
    unsigned short u;
    __builtin_memcpy(&u, &hv, 2);
    __hip_atomic_store((unsigned short*)p, u, __ATOMIC_RELAXED, __HIP_MEMORY_SCOPE_AGENT);
}

// Two-level grid barrier: 16 groups x 16 WGs, separate LLC lines.
// Release side: NO cache fence (write-through h stores). Acquire side: one
// buffer_inv per CU (L1 + XCD-L2) so subsequent CACHED h loads refill from LLC.
__device__ __forceinline__ void gbar_arrive(char* bar, unsigned epoch, int wg) {
    unsigned* gcnt = (unsigned*)(bar + (wg & 15) * 256);
    unsigned old = __hip_atomic_fetch_add(gcnt, 1u, __ATOMIC_RELAXED, __HIP_MEMORY_SCOPE_AGENT);
    if (old == epoch * 16u - 1u) {        // last of my group
        unsigned* rcnt = (unsigned*)(bar + 4096);
        unsigned rold = __hip_atomic_fetch_add(rcnt, 1u, __ATOMIC_RELAXED, __HIP_MEMORY_SCOPE_AGENT);
        if (rold == epoch * 16u - 1u) {   // last group overall
            unsigned* flag = (unsigned*)(bar + 4352);
            __hip_atomic_store(flag, epoch, __ATOMIC_RELAXED, __HIP_MEMORY_SCOPE_AGENT);
        }
    }
}
__device__ __forceinline__ void gbar_wait(char* bar, unsigned epoch) {
    unsigned* flag = (unsigned*)(bar + 4352);
    while (__hip_atomic_load(flag, __ATOMIC_RELAXED, __HIP_MEMORY_SCOPE_AGENT) < epoch)
        __builtin_amdgcn_s_sleep(1);
    __builtin_amdgcn_fence(__ATOMIC_ACQUIRE, "agent");  // inv L1 + XCD L2
}

__global__ void __launch_bounds__(512)
lstm_persist(const float* __restrict__ x,
             const float* __restrict__ Wih0, const float* __restrict__ Whh0,
             const float* __restrict__ bih0, const float* __restrict__ bhh0,
             const float* __restrict__ Wih1, const float* __restrict__ Whh1,
             const float* __restrict__ bih1, const float* __restrict__ bhh1,
             const float* __restrict__ Wd, const float* __restrict__ bd,
             float* __restrict__ out, char* __restrict__ wsc)
{
    cg::grid_group grid = cg::this_grid();
    const int wg   = blockIdx.x;      // 0..255, owns h-cols [wg*4, wg*4+4)
    const int tid  = threadIdx.x;     // 0..511
    const int wave = tid >> 6;        // 0..7, owns batch rows [wave*16, wave*16+16)
    const int lane = tid & 63;
    const int l15  = lane & 15;
    const int quad = lane >> 4;

    _Float16* h0b = (_Float16*)(wsc + H0_OFF);   // [2][128][1024]
    _Float16* h1b = (_Float16*)(wsc + H1_OFF);   // [2][128][1024]
    _Float16* x16 = (_Float16*)(wsc + X16_OFF);  // [128][256][128]
    char* bar = wsc + BAR_OFF;

    extern __shared__ char smem[];
    _Float16* w0l = (_Float16*)(smem);            // [16][1160]
    _Float16* w1l = (_Float16*)(smem + 37120);    // [16][2056]
    float*    gs0 = (float*)(smem + 102912);      // [16][132] col-major
    float*    gs1 = (float*)(smem + 111360);      // [16][132]
    float*    bs0 = (float*)(smem + 119808);      // [16]
    float*    bs1 = (float*)(smem + 119808 + 64); // [16]

    // ---------- init: stage this WG's weight slice into LDS (fp16) ----------
    for (int i = tid; i < 16 * 1152; i += 512) {
        int c = i / 1152, k = i - c * 1152;
        int gcol = ((c >> 2) << 10) + (wg << 2) + (c & 3);
        float v = (k < NIN) ? Wih0[gcol * NIN + k] : Whh0[gcol * NH + (k - NIN)];
        w0l[c * W0STRIDE + k] = (_Float16)v;
    }
    for (int i = tid; i < 16 * 2048; i += 512) {
        int c = i >> 11, k = i & 2047;
        int gcol = ((c >> 2) << 10) + (wg << 2) + (c & 3);
        float v = (k < NH) ? Wih1[gcol * NH + k] : Whh1[gcol * NH + (k - NH)];
        w1l[c * W1STRIDE + k] = (_Float16)v;
    }
    if (tid < 16) {
        int c = tid;
        int gcol = ((c >> 2) << 10) + (wg << 2) + (c & 3);
        bs0[c] = bih0[gcol] + bhh0[gcol];
        bs1[c] = bih1[gcol] + bhh1[gcol];
    }

    // ---------- init: zero h bufs, convert x to fp16, reset barrier state ----------
    {
        const int gtid = wg * 512 + tid;
        const int gsz  = 256 * 512;  // 131072
        float* hz = (float*)wsc;     // both h bufs = 1 MiB = 262144 floats
        for (int i = gtid; i < 262144; i += gsz) hz[i] = 0.0f;
        for (int i = gtid; i < NB * NT * NIN; i += gsz) x16[i] = (_Float16)x[i];
        if (wg == 0 && tid < 18) {   // d_ws is poisoned 0xAA each run
            if (tid < 16)       *(unsigned*)(bar + tid * 256) = 0u;  // group counters
            else if (tid == 16) *(unsigned*)(bar + 4096) = 0u;       // root counter
            else                *(unsigned*)(bar + 4352) = 0u;       // flag
        }
    }
    // one slow cg sync with full fences: publishes zeros (into LLC) + barrier state
    __builtin_amdgcn_fence(__ATOMIC_RELEASE, "agent");
    grid.sync();
    __builtin_amdgcn_fence(__ATOMIC_ACQUIRE, "agent");

    float c0 = 0.0f, c1 = 0.0f;          // persistent cell state, 1 (b,hcol) pair/thread
    const int b_act = tid >> 2;          // batch row for activation stage
    const int jl    = tid & 3;           // local h-col
    const int hcol  = (wg << 2) + jl;

    // B-fragment row bases in LDS (n = l15), A k-offset quad*8 baked in
    const _Float16* w0row = w0l + l15 * W0STRIDE + quad * 8;
    const _Float16* w1row = w1l + l15 * W1STRIDE + quad * 8;

    // x-part of layer0 gates for step p (h-independent): K = 0..127
    auto xpart = [&](int p) -> floatx4 {
        floatx4 acc = {0.f, 0.f, 0.f, 0.f};
        const _Float16* arow_x = x16 + (size_t)(wave * 16 + l15) * (NT * NIN) + p * NIN + quad * 8;
        #pragma unroll
        for (int kc = 0; kc < 4; ++kc) {
            half8 a = *(const half8*)(arow_x + kc * 32);
            half8 b = *(const half8*)(w0row + kc * 32);
            acc = __builtin_amdgcn_mfma_f32_16x16x32_f16(a, b, acc, 0, 0, 0);
        }
        return acc;
    };

    floatx4 accx = xpart(0);   // prologue for p=0

    // pipeline: phase p computes h0[p] (p<NT) and h1[p-1] (p>=1)
    for (int p = 0; p <= NT; ++p) {
        const _Float16* h0prev = h0b + ((p - 1) & 1) * (NB * NH);  // h0[p-1]
        const _Float16* h1pp   = h1b + (p & 1) * (NB * NH);        // h1[p-2]

        floatx4 acc0  = accx;  // x contribution precomputed during prior barrier window
        floatx4 acc1  = {0.f, 0.f, 0.f, 0.f};
        floatx4 acc1b = {0.f, 0.f, 0.f, 0.f};

        const _Float16* arow_h0 = h0prev + (size_t)(wave * 16 + l15) * NH + quad * 8;
        const _Float16* arow_h1 = h1pp   + (size_t)(wave * 16 + l15) * NH + quad * 8;
        const _Float16* b0  = w0row + NIN;   // layer0 W_hh B-cols
        const _Float16* b1h = w1row + NH;    // layer1 W_hh B-cols

        // MLP-batched K loop: issue 16 independent A-loads (8 h0 + 8 h1) per
        // chunk before any MFMA consumes them; three independent acc chains.
        if (p >= 1 && p < NT) {
            #pragma unroll
            for (int c = 0; c < 4; ++c) {
                half8 a0[8], a1[8];
                #pragma unroll
                for (int j = 0; j < 8; ++j) a0[j] = *(const half8*)(arow_h0 + (c * 8 + j) * 32);
                #pragma unroll
                for (int j = 0; j < 8; ++j) a1[j] = *(const half8*)(arow_h1 + (c * 8 + j) * 32);
                #pragma unroll
                for (int j = 0; j < 8; ++j) {
                    half8 v0 = *(const half8*)(b0    + (c * 8 + j) * 32);
                    half8 v1 = *(const half8*)(w1row + (c * 8 + j) * 32);
                    half8 v2 = *(const half8*)(b1h   + (c * 8 + j) * 32);
                    acc0  = __builtin_amdgcn_mfma_f32_16x16x32_f16(a0[j], v0, acc0, 0, 0, 0);
                    acc1  = __builtin_amdgcn_mfma_f32_16x16x32_f16(a0[j], v1, acc1, 0, 0, 0);
                    acc1b = __builtin_amdgcn_mfma_f32_16x16x32_f16(a1[j], v2, acc1b, 0, 0, 0);
                }
            }
        } else if (p == NT) {  // layer1 only: h0[NT-1]·W_ih1 + h1[NT-2]·W_hh1
            #pragma unroll
            for (int c = 0; c < 4; ++c) {
                half8 a0[8], a1[8];
                #pragma unroll
                for (int j = 0; j < 8; ++j) a0[j] = *(const half8*)(arow_h0 + (c * 8 + j) * 32);
                #pragma unroll
                for (int j = 0; j < 8; ++j) a1[j] = *(const half8*)(arow_h1 + (c * 8 + j) * 32);
                #pragma unroll
                for (int j = 0; j < 8; ++j) {
                    half8 v1 = *(const half8*)(w1row + (c * 8 + j) * 32);
                    half8 v2 = *(const half8*)(b1h   + (c * 8 + j) * 32);
                    acc1  = __builtin_amdgcn_mfma_f32_16x16x32_f16(a0[j], v1, acc1, 0, 0, 0);
                    acc1b = __builtin_amdgcn_mfma_f32_16x16x32_f16(a1[j], v2, acc1b, 0, 0, 0);
                }
            }
        }
        // p == 0: h buffers are all zeros — gate h-contributions are zero; skip.
        acc1 = acc1 + acc1b;

        // stash gate tiles to LDS, col-major: rows quad*4+r contiguous -> one b128
        if (p < NT) *(floatx4*)&gs0[l15 * GSTRIDE + wave * 16 + quad * 4] = acc0;
        if (p >= 1) *(floatx4*)&gs1[l15 * GSTRIDE + wave * 16 + quad * 4] = acc1;
        __syncthreads();

        // activation: 1 (b, hcol) pair per thread; gate cols c = gate*4 + jl
        if (p < NT) {
            float gi = gs0[(jl)      * GSTRIDE + b_act] + bs0[jl];
            float gf = gs0[(4 + jl)  * GSTRIDE + b_act] + bs0[4 + jl];
            float gg = gs0[(8 + jl)  * GSTRIDE + b_act] + bs0[8 + jl];
            float go = gs0[(12 + jl) * GSTRIDE + b_act] + bs0[12 + jl];
            c0 = sigm(gf) * c0 + sigm(gi) * tanh_fast(gg);
            float h = sigm(go) * tanh_fast(c0);
            st2_agent(h0b + (p & 1) * (NB * NH) + b_act * NH + hcol, h);
        }
        if (p >= 1) {
            float gi = gs1[(jl)      * GSTRIDE + b_act] + bs1[jl];
            float gf = gs1[(4 + jl)  * GSTRIDE + b_act] + bs1[4 + jl];
            float gg = gs1[(8 + jl)  * GSTRIDE + b_act] + bs1[8 + jl];
            float go = gs1[(12 + jl) * GSTRIDE + b_act] + bs1[12 + jl];
            c1 = sigm(gf) * c1 + sigm(gi) * tanh_fast(gg);
            float h = sigm(go) * tanh_fast(c1);
            st2_agent(h1b + ((p - 1) & 1) * (NB * NH) + b_act * NH + hcol, h);
        }

        // ---- barrier with overlap: arrive (no release fence needed),
        // ---- compute next x-part during spin window, then wait + acquire-inv.
        __syncthreads();                       // drains vmcnt: h-stores committed at LLC
        if (tid == 0) gbar_arrive(bar, (unsigned)(p + 1), wg);
        if (p + 1 < NT) accx = xpart(p + 1);   // h-independent work hides spin latency
        if (tid == 0) gbar_wait(bar, (unsigned)(p + 1));
        __syncthreads();
    }

    // dense head, parallel over batch: WG b computes out[b][0..1] from h1[255] (parity 1)
    // (final gbar_wait's acquire fence makes cached loads of h1 fresh)
    if (wg < NB) {
        const _Float16* hrow = h1b + (NB * NH) + wg * NH;
        float hk0 = (float)hrow[tid * 2];
        float hk1 = (float)hrow[tid * 2 + 1];
        float p0 = hk0 * Wd[tid * 2] + hk1 * Wd[tid * 2 + 1];
        float p1 = hk0 * Wd[NH + tid * 2] + hk1 * Wd[NH + tid * 2 + 1];
        #pragma unroll
        for (int off = 32; off; off >>= 1) {
            p0 += __shfl_down(p0, off);
            p1 += __shfl_down(p1, off);
        }
        float* red = gs0;  // reuse LDS (all threads past final __syncthreads)
        if (lane == 0) { red[wave * 2] = p0; red[wave * 2 + 1] = p1; }
        __syncthreads();
        if (tid < 2) {
            float s = bd[tid];
            #pragma unroll
            for (int w = 0; w < 8; ++w) s += red[w * 2 + tid];
            out[wg * 2 + tid] = tanhf(s);
        }
    }
}

extern "C" void kernel_launch(void* const* d_in, const int* in_sizes, int n_in,
                              void* d_out, int out_size, void* d_ws, size_t ws_size,
                              hipStream_t stream) {
    const float* x    = (const float*)d_in[0];
    const float* Wih0 = (const float*)d_in[1];
    const float* Whh0 = (const float*)d_in[2];
    const float* bih0 = (const float*)d_in[3];
    const float* bhh0 = (const float*)d_in[4];
    const float* Wih1 = (const float*)d_in[5];
    const float* Whh1 = (const float*)d_in[6];
    const float* bih1 = (const float*)d_in[7];
    const float* bhh1 = (const float*)d_in[8];
    const float* Wd   = (const float*)d_in[9];
    const float* bd   = (const float*)d_in[10];
    float* out = (float*)d_out;
    char* ws = (char*)d_ws;

    hipFuncSetAttribute((const void*)lstm_persist,
                        hipFuncAttributeMaxDynamicSharedMemorySize, LDS_BYTES);

    void* kargs[] = { &x, &Wih0, &Whh0, &bih0, &bhh0, &Wih1, &Whh1, &bih1, &bhh1,
                      &Wd, &bd, &out, &ws };
    hipLaunchCooperativeKernel((void*)lstm_persist, dim3(256), dim3(512),
                               kargs, LDS_BYTES, stream);
}

// Round 8
// 4695.436 us; speedup vs baseline: 1.7392x; 1.0808x over previous
//
#include <hip/hip_runtime.h>
#include <hip/hip_fp16.h>
#include <hip/hip_cooperative_groups.h>

namespace cg = cooperative_groups;

typedef _Float16 half8 __attribute__((ext_vector_type(8)));
typedef float floatx4 __attribute__((ext_vector_type(4)));

#define NB 128
#define NT 256
#define NIN 128
#define NH 1024

// ws layout (bytes): 8-deep h rings (so L2-inv is only needed every 8th phase)
// + fp16 x copy + barrier state
#define H0_OFF   0u          // 8 bufs x 128*1024 half = 2097152 B
#define H1_OFF   2097152u    // 2097152 B
#define X16_OFF  4194304u    // 128*256*128 half = 8388608 B
#define BAR_OFF  12582912u   // barrier region: 16 group lines @256B, root @4096, flag @4352

// LDS layout (bytes), carved from extern __shared__:
//  w0l: 16 cols x (1152+8) half = 37120
//  w1l: 16 cols x (2048+8) half = 65792   (base 37120)
//  gs0: 16 cols x 132 float     =  8448   (base 102912) col-major gate tile
//  gs1: 16 cols x 132 float     =  8448   (base 111360)
//  bs0/bs1: 16+16 float         =   128   (base 119808) -> total 119936
#define W0STRIDE 1160
#define W1STRIDE 2056
#define GSTRIDE  132
#define LDS_BYTES 119936

__device__ __forceinline__ float sigm(float x) { return 1.0f / (1.0f + __expf(-x)); }
__device__ __forceinline__ float tanh_fast(float x) { return 1.0f - 2.0f / (__expf(2.0f * x) + 1.0f); }

// h STORES: agent-scope relaxed atomic 2B stores — write-through past the
// non-coherent XCD L2 straight to LLC. After __syncthreads' vmcnt(0) drain
// these are globally visible: NO release (wbl2) fence needed anywhere.
__device__ __forceinline__ void st2_agent(_Float16* p, float v) {
    _Float16 hv = (_Float16)v;
    unsigned short u;
    __builtin_memcpy(&u, &hv, 2);
    __hip_atomic_store((unsigned short*)p, u, __ATOMIC_RELAXED, __HIP_MEMORY_SCOPE_AGENT);
}

// Two-level grid barrier: 16 groups x 16 WGs, separate LLC lines.
// Release side: NO cache fence (write-through h stores).
// Acquire side, ring-aware: h ring buffers are fresh addresses for 8
// consecutive phases, so the expensive agent fence (buffer_inv sc1: L1 +
// whole-XCD-L2 invalidate) is only needed every 8th epoch, right before ring
// addresses are reused. Other epochs need only a cheap per-CU L1 invalidate
// (buffer_inv sc0) to kill any (capacity-surviving) stale L1 h lines.
__device__ __forceinline__ void gbar_arrive(char* bar, unsigned epoch, int wg) {
    unsigned* gcnt = (unsigned*)(bar + (wg & 15) * 256);
    unsigned old = __hip_atomic_fetch_add(gcnt, 1u, __ATOMIC_RELAXED, __HIP_MEMORY_SCOPE_AGENT);
    if (old == epoch * 16u - 1u) {        // last of my group
        unsigned* rcnt = (unsigned*)(bar + 4096);
        unsigned rold = __hip_atomic_fetch_add(rcnt, 1u, __ATOMIC_RELAXED, __HIP_MEMORY_SCOPE_AGENT);
        if (rold == epoch * 16u - 1u) {   // last group overall
            unsigned* flag = (unsigned*)(bar + 4352);
            __hip_atomic_store(flag, epoch, __ATOMIC_RELAXED, __HIP_MEMORY_SCOPE_AGENT);
        }
    }
}
__device__ __forceinline__ void gbar_wait(char* bar, unsigned epoch) {
    unsigned* flag = (unsigned*)(bar + 4352);
    while (__hip_atomic_load(flag, __ATOMIC_RELAXED, __HIP_MEMORY_SCOPE_AGENT) < epoch)
        __builtin_amdgcn_s_sleep(1);
    if ((epoch & 7u) == 0u) {
        // ring-reuse boundary: invalidate L1 + XCD L2 so next 8 phases' cached
        // h loads (and the dense head) refill fresh from LLC
        __builtin_amdgcn_fence(__ATOMIC_ACQUIRE, "agent");
    } else {
        // L1-only invalidate: per-CU, cheap; XCD L2 keeps h/x lines warm
        asm volatile("s_waitcnt vmcnt(0)\n\tbuffer_inv sc0" ::: "memory");
    }
}

__global__ void __launch_bounds__(512)
lstm_persist(const float* __restrict__ x,
             const float* __restrict__ Wih0, const float* __restrict__ Whh0,
             const float* __restrict__ bih0, const float* __restrict__ bhh0,
             const float* __restrict__ Wih1, const float* __restrict__ Whh1,
             const float* __restrict__ bih1, const float* __restrict__ bhh1,
             const float* __restrict__ Wd, const float* __restrict__ bd,
             float* __restrict__ out, char* __restrict__ wsc)
{
    cg::grid_group grid = cg::this_grid();
    const int wg   = blockIdx.x;      // 0..255, owns h-cols [wg*4, wg*4+4)
    const int tid  = threadIdx.x;     // 0..511
    const int wave = tid >> 6;        // 0..7, owns batch rows [wave*16, wave*16+16)
    const int lane = tid & 63;
    const int l15  = lane & 15;
    const int quad = lane >> 4;

    _Float16* h0b = (_Float16*)(wsc + H0_OFF);   // [8][128][1024] ring: h0[t] in buf t&7
    _Float16* h1b = (_Float16*)(wsc + H1_OFF);   // [8][128][1024] ring: h1[t] in buf t&7
    _Float16* x16 = (_Float16*)(wsc + X16_OFF);  // [128][256][128]
    char* bar = wsc + BAR_OFF;

    extern __shared__ char smem[];
    _Float16* w0l = (_Float16*)(smem);            // [16][1160]
    _Float16* w1l = (_Float16*)(smem + 37120);    // [16][2056]
    float*    gs0 = (float*)(smem + 102912);      // [16][132] col-major
    float*    gs1 = (float*)(smem + 111360);      // [16][132]
    float*    bs0 = (float*)(smem + 119808);      // [16]
    float*    bs1 = (float*)(smem + 119808 + 64); // [16]

    // ---------- init: stage this WG's weight slice into LDS (fp16) ----------
    for (int i = tid; i < 16 * 1152; i += 512) {
        int c = i / 1152, k = i - c * 1152;
        int gcol = ((c >> 2) << 10) + (wg << 2) + (c & 3);
        float v = (k < NIN) ? Wih0[gcol * NIN + k] : Whh0[gcol * NH + (k - NIN)];
        w0l[c * W0STRIDE + k] = (_Float16)v;
    }
    for (int i = tid; i < 16 * 2048; i += 512) {
        int c = i >> 11, k = i & 2047;
        int gcol = ((c >> 2) << 10) + (wg << 2) + (c & 3);
        float v = (k < NH) ? Wih1[gcol * NH + k] : Whh1[gcol * NH + (k - NH)];
        w1l[c * W1STRIDE + k] = (_Float16)v;
    }
    if (tid < 16) {
        int c = tid;
        int gcol = ((c >> 2) << 10) + (wg << 2) + (c & 3);
        bs0[c] = bih0[gcol] + bhh0[gcol];
        bs1[c] = bih1[gcol] + bhh1[gcol];
    }

    // ---------- init: zero h rings, convert x to fp16, reset barrier state ----------
    {
        const int gtid = wg * 512 + tid;
        const int gsz  = 256 * 512;  // 131072
        float* hz = (float*)wsc;     // both rings = 4 MiB = 1048576 floats
        for (int i = gtid; i < 1048576; i += gsz) hz[i] = 0.0f;
        for (int i = gtid; i < NB * NT * NIN; i += gsz) x16[i] = (_Float16)x[i];
        if (wg == 0 && tid < 18) {   // d_ws is poisoned 0xAA each run
            if (tid < 16)       *(unsigned*)(bar + tid * 256) = 0u;  // group counters
            else if (tid == 16) *(unsigned*)(bar + 4096) = 0u;       // root counter
            else                *(unsigned*)(bar + 4352) = 0u;       // flag
        }
    }
    // one slow cg sync with full fences: publishes zeros (into LLC) + barrier state
    __builtin_amdgcn_fence(__ATOMIC_RELEASE, "agent");
    grid.sync();
    __builtin_amdgcn_fence(__ATOMIC_ACQUIRE, "agent");

    float c0 = 0.0f, c1 = 0.0f;          // persistent cell state, 1 (b,hcol) pair/thread
    const int b_act = tid >> 2;          // batch row for activation stage
    const int jl    = tid & 3;           // local h-col
    const int hcol  = (wg << 2) + jl;

    // B-fragment row bases in LDS (n = l15), A k-offset quad*8 baked in
    const _Float16* w0row = w0l + l15 * W0STRIDE + quad * 8;
    const _Float16* w1row = w1l + l15 * W1STRIDE + quad * 8;

    // x-part of layer0 gates for step p (h-independent): K = 0..127
    auto xpart = [&](int p) -> floatx4 {
        floatx4 acc = {0.f, 0.f, 0.f, 0.f};
        const _Float16* arow_x = x16 + (size_t)(wave * 16 + l15) * (NT * NIN) + p * NIN + quad * 8;
        #pragma unroll
        for (int kc = 0; kc < 4; ++kc) {
            half8 a = *(const half8*)(arow_x + kc * 32);
            half8 b = *(const half8*)(w0row + kc * 32);
            acc = __builtin_amdgcn_mfma_f32_16x16x32_f16(a, b, acc, 0, 0, 0);
        }
        return acc;
    };

    floatx4 accx = xpart(0);   // prologue for p=0

    // pipeline: phase p computes h0[p] (p<NT) and h1[p-1] (p>=1)
    // ring reads: h0[p-1] -> buf (p+7)&7 ; h1[p-2] -> buf (p+6)&7 (zeros pre-start)
    for (int p = 0; p <= NT; ++p) {
        const _Float16* h0prev = h0b + (size_t)((p + 7) & 7) * (NB * NH);  // h0[p-1]
        const _Float16* h1pp   = h1b + (size_t)((p + 6) & 7) * (NB * NH);  // h1[p-2]

        floatx4 acc0  = accx;  // x contribution precomputed during prior barrier window
        floatx4 acc1  = {0.f, 0.f, 0.f, 0.f};
        floatx4 acc1b = {0.f, 0.f, 0.f, 0.f};

        const _Float16* arow_h0 = h0prev + (size_t)(wave * 16 + l15) * NH + quad * 8;
        const _Float16* arow_h1 = h1pp   + (size_t)(wave * 16 + l15) * NH + quad * 8;
        const _Float16* b0  = w0row + NIN;   // layer0 W_hh B-cols
        const _Float16* b1h = w1row + NH;    // layer1 W_hh B-cols

        // MLP-batched K loop: 16 independent A-loads (8 h0 + 8 h1) per chunk,
        // three independent acc chains.
        if (p >= 1 && p < NT) {
            #pragma unroll
            for (int c = 0; c < 4; ++c) {
                half8 a0[8], a1[8];
                #pragma unroll
                for (int j = 0; j < 8; ++j) a0[j] = *(const half8*)(arow_h0 + (c * 8 + j) * 32);
                #pragma unroll
                for (int j = 0; j < 8; ++j) a1[j] = *(const half8*)(arow_h1 + (c * 8 + j) * 32);
                #pragma unroll
                for (int j = 0; j < 8; ++j) {
                    half8 v0 = *(const half8*)(b0    + (c * 8 + j) * 32);
                    half8 v1 = *(const half8*)(w1row + (c * 8 + j) * 32);
                    half8 v2 = *(const half8*)(b1h   + (c * 8 + j) * 32);
                    acc0  = __builtin_amdgcn_mfma_f32_16x16x32_f16(a0[j], v0, acc0, 0, 0, 0);
                    acc1  = __builtin_amdgcn_mfma_f32_16x16x32_f16(a0[j], v1, acc1, 0, 0, 0);
                    acc1b = __builtin_amdgcn_mfma_f32_16x16x32_f16(a1[j], v2, acc1b, 0, 0, 0);
                }
            }
        } else if (p == NT) {  // layer1 only: h0[NT-1]·W_ih1 + h1[NT-2]·W_hh1
            #pragma unroll
            for (int c = 0; c < 4; ++c) {
                half8 a0[8], a1[8];
                #pragma unroll
                for (int j = 0; j < 8; ++j) a0[j] = *(const half8*)(arow_h0 + (c * 8 + j) * 32);
                #pragma unroll
                for (int j = 0; j < 8; ++j) a1[j] = *(const half8*)(arow_h1 + (c * 8 + j) * 32);
                #pragma unroll
                for (int j = 0; j < 8; ++j) {
                    half8 v1 = *(const half8*)(w1row + (c * 8 + j) * 32);
                    half8 v2 = *(const half8*)(b1h   + (c * 8 + j) * 32);
                    acc1  = __builtin_amdgcn_mfma_f32_16x16x32_f16(a0[j], v1, acc1, 0, 0, 0);
                    acc1b = __builtin_amdgcn_mfma_f32_16x16x32_f16(a1[j], v2, acc1b, 0, 0, 0);
                }
            }
        }
        // p == 0: h buffers are all zeros — gate h-contributions are zero; skip.
        acc1 = acc1 + acc1b;

        // stash gate tiles to LDS, col-major: rows quad*4+r contiguous -> one b128
        if (p < NT) *(floatx4*)&gs0[l15 * GSTRIDE + wave * 16 + quad * 4] = acc0;
        if (p >= 1) *(floatx4*)&gs1[l15 * GSTRIDE + wave * 16 + quad * 4] = acc1;
        __syncthreads();

        // activation: 1 (b, hcol) pair per thread; gate cols c = gate*4 + jl
        if (p < NT) {
            float gi = gs0[(jl)      * GSTRIDE + b_act] + bs0[jl];
            float gf = gs0[(4 + jl)  * GSTRIDE + b_act] + bs0[4 + jl];
            float gg = gs0[(8 + jl)  * GSTRIDE + b_act] + bs0[8 + jl];
            float go = gs0[(12 + jl) * GSTRIDE + b_act] + bs0[12 + jl];
            c0 = sigm(gf) * c0 + sigm(gi) * tanh_fast(gg);
            float h = sigm(go) * tanh_fast(c0);
            st2_agent(h0b + (size_t)(p & 7) * (NB * NH) + b_act * NH + hcol, h);   // h0[p]
        }
        if (p >= 1) {
            float gi = gs1[(jl)      * GSTRIDE + b_act] + bs1[jl];
            float gf = gs1[(4 + jl)  * GSTRIDE + b_act] + bs1[4 + jl];
            float gg = gs1[(8 + jl)  * GSTRIDE + b_act] + bs1[8 + jl];
            float go = gs1[(12 + jl) * GSTRIDE + b_act] + bs1[12 + jl];
            c1 = sigm(gf) * c1 + sigm(gi) * tanh_fast(gg);
            float h = sigm(go) * tanh_fast(c1);
            st2_agent(h1b + (size_t)((p + 7) & 7) * (NB * NH) + b_act * NH + hcol, h);  // h1[p-1]
        }

        // ---- barrier with overlap: arrive (no release fence needed),
        // ---- compute next x-part during spin window, then wait + scoped inv.
        __syncthreads();                       // drains vmcnt: h-stores committed at LLC
        if (tid == 0) gbar_arrive(bar, (unsigned)(p + 1), wg);
        if (p + 1 < NT) accx = xpart(p + 1);   // h-independent work hides spin latency
        if (tid == 0) gbar_wait(bar, (unsigned)(p + 1));
        __syncthreads();
    }

    // dense head, parallel over batch: WG b computes out[b][0..1] from h1[255]
    // (ring buf 255&7 = 7; L2-inv at epoch 256 + L1-inv at epoch 257 make
    // cached loads fresh)
    if (wg < NB) {
        const _Float16* hrow = h1b + (size_t)7 * (NB * NH) + wg * NH;
        float hk0 = (float)hrow[tid * 2];
        float hk1 = (float)hrow[tid * 2 + 1];
        float p0 = hk0 * Wd[tid * 2] + hk1 * Wd[tid * 2 + 1];
        float p1 = hk0 * Wd[NH + tid * 2] + hk1 * Wd[NH + tid * 2 + 1];
        #pragma unroll
        for (int off = 32; off; off >>= 1) {
            p0 += __shfl_down(p0, off);
            p1 += __shfl_down(p1, off);
        }
        float* red = gs0;  // reuse LDS (all threads past final __syncthreads)
        if (lane == 0) { red[wave * 2] = p0; red[wave * 2 + 1] = p1; }
        __syncthreads();
        if (tid < 2) {
            float s = bd[tid];
            #pragma unroll
            for (int w = 0; w < 8; ++w) s += red[w * 2 + tid];
            out[wg * 2 + tid] = tanhf(s);
        }
    }
}

extern "C" void kernel_launch(void* const* d_in, const int* in_sizes, int n_in,
                              void* d_out, int out_size, void* d_ws, size_t ws_size,
                              hipStream_t stream) {
    const float* x    = (const float*)d_in[0];
    const float* Wih0 = (const float*)d_in[1];
    const float* Whh0 = (const float*)d_in[2];
    const float* bih0 = (const float*)d_in[3];
    const float* bhh0 = (const float*)d_in[4];
    const float* Wih1 = (const float*)d_in[5];
    const float* Whh1 = (const float*)d_in[6];
    const float* bih1 = (const float*)d_in[7];
    const float* bhh1 = (const float*)d_in[8];
    const float* Wd   = (const float*)d_in[9];
    const float* bd   = (const float*)d_in[10];
    float* out = (float*)d_out;
    char* ws = (char*)d_ws;

    hipFuncSetAttribute((const void*)lstm_persist,
                        hipFuncAttributeMaxDynamicSharedMemorySize, LDS_BYTES);

    void* kargs[] = { &x, &Wih0, &Whh0, &bih0, &bhh0, &Wih1, &Whh1, &bih1, &bhh1,
                      &Wd, &bd, &out, &ws };
    hipLaunchCooperativeKernel((void*)lstm_persist, dim3(256), dim3(512),
                               kargs, LDS_BYTES, stream);
}